// Round 2
// baseline (60.872 us; speedup 1.0000x reference)
//
#include <hip/hip_runtime.h>
#include <math.h>

#define D_DIM 1024
#define TEMP_INV 14.285714285714286f   // 1/0.07
#define L2EPS 1e-12f

// ws layout (floats):
// [0*N .. 1*N)  nv   = ||v_k||
// [1*N .. 2*N)  na   = ||a_k||
// [2*N .. 3*N)  nt   = ||t_k||
// [3*N .. 4*N)  dva  = v_k . a_k
// [4*N .. 5*N)  dvt  = v_k . t_k
// [5*N .. 6*N)  d0a  = v_0 . a_k
// [6*N .. 7*N)  d0t  = v_0 . t_k

__device__ __forceinline__ float dot4(const float4 p, const float4 q) {
    return p.x*q.x + p.y*q.y + p.z*q.z + p.w*q.w;
}

__global__ __launch_bounds__(256) void nce_rowstats(
    const float* __restrict__ v, const float* __restrict__ a,
    const float* __restrict__ t, float* __restrict__ ws, int N)
{
    __shared__ float4 v0s[256];          // row 0 of v (4 KB)
    const int tid  = threadIdx.x;
    const int wave = tid >> 6;
    const int lane = tid & 63;
    const int row  = blockIdx.x * 4 + wave;

    // stage v0 into LDS (one float4 per thread)
    v0s[tid] = ((const float4*)v)[tid];
    __syncthreads();

    if (row >= N) return;

    const float4* vr = (const float4*)(v + (size_t)row * D_DIM);
    const float4* ar = (const float4*)(a + (size_t)row * D_DIM);
    const float4* tr = (const float4*)(t + (size_t)row * D_DIM);

    // ---- issue ALL 12 streaming loads before any use (max MLP) ----
    const float4 V0 = vr[lane      ];
    const float4 V1 = vr[lane +  64];
    const float4 V2 = vr[lane + 128];
    const float4 V3 = vr[lane + 192];
    const float4 A0 = ar[lane      ];
    const float4 A1 = ar[lane +  64];
    const float4 A2 = ar[lane + 128];
    const float4 A3 = ar[lane + 192];
    const float4 T0 = tr[lane      ];
    const float4 T1 = tr[lane +  64];
    const float4 T2 = tr[lane + 128];
    const float4 T3 = tr[lane + 192];

    const float4 Z0 = v0s[lane      ];
    const float4 Z1 = v0s[lane +  64];
    const float4 Z2 = v0s[lane + 128];
    const float4 Z3 = v0s[lane + 192];

    float sv  = dot4(V0,V0) + dot4(V1,V1) + dot4(V2,V2) + dot4(V3,V3);
    float sa  = dot4(A0,A0) + dot4(A1,A1) + dot4(A2,A2) + dot4(A3,A3);
    float st  = dot4(T0,T0) + dot4(T1,T1) + dot4(T2,T2) + dot4(T3,T3);
    float dva = dot4(V0,A0) + dot4(V1,A1) + dot4(V2,A2) + dot4(V3,A3);
    float dvt = dot4(V0,T0) + dot4(V1,T1) + dot4(V2,T2) + dot4(V3,T3);
    float d0a = dot4(Z0,A0) + dot4(Z1,A1) + dot4(Z2,A2) + dot4(Z3,A3);
    float d0t = dot4(Z0,T0) + dot4(Z1,T1) + dot4(Z2,T2) + dot4(Z3,T3);

    // wave (64-lane) butterfly reduce of 7 values
    #pragma unroll
    for (int off = 32; off >= 1; off >>= 1) {
        sv  += __shfl_down(sv,  off);
        sa  += __shfl_down(sa,  off);
        st  += __shfl_down(st,  off);
        dva += __shfl_down(dva, off);
        dvt += __shfl_down(dvt, off);
        d0a += __shfl_down(d0a, off);
        d0t += __shfl_down(d0t, off);
    }

    if (lane == 0) {
        ws[0*N + row] = sqrtf(sv);
        ws[1*N + row] = sqrtf(sa);
        ws[2*N + row] = sqrtf(st);
        ws[3*N + row] = dva;
        ws[4*N + row] = dvt;
        ws[5*N + row] = d0a;
        ws[6*N + row] = d0t;
    }
}

__device__ __forceinline__ float block_reduce_1024(float val, float* sred) {
    // 1024 threads = 16 waves. sred must hold >= 16 floats.
    const int lane = threadIdx.x & 63;
    const int wave = threadIdx.x >> 6;
    __syncthreads();   // protect sred reuse across successive calls
    #pragma unroll
    for (int off = 32; off >= 1; off >>= 1) val += __shfl_down(val, off);
    if (lane == 0) sred[wave] = val;
    __syncthreads();
    float r = 0.f;
    if (wave == 0) {
        r = (lane < 16) ? sred[lane] : 0.f;
        #pragma unroll
        for (int off = 8; off >= 1; off >>= 1) r += __shfl_down(r, off);
        if (lane == 0) sred[0] = r;
    }
    __syncthreads();
    return sred[0];
}

__global__ __launch_bounds__(1024) void nce_finalize(
    const float* __restrict__ v, const float* __restrict__ a,
    const float* __restrict__ t, const float* __restrict__ ws,
    float* __restrict__ out, int N)
{
    __shared__ float sred[16];
    const int tid = threadIdx.x;

    const float* nv  = ws + 0 * (size_t)N;
    const float* na  = ws + 1 * (size_t)N;
    const float* nt  = ws + 2 * (size_t)N;
    const float* dva = ws + 3 * (size_t)N;
    const float* dvt = ws + 4 * (size_t)N;
    const float* d0a = ws + 5 * (size_t)N;
    const float* d0t = ws + 6 * (size_t)N;

    const float nv0 = fmaxf(nv[0], L2EPS);
    const float nv1 = fmaxf(nv[1], L2EPS);
    const float na0 = fmaxf(na[0], L2EPS);
    const float nt0 = fmaxf(nt[0], L2EPS);

    // ---- Phase A: extras ea = v1.a0, et = v1.t0 (D=1024, one elem/thread)
    float pea = v[D_DIM + tid] * a[tid];
    float pet = v[D_DIM + tid] * t[tid];
    const float ea = block_reduce_1024(pea, sred);
    const float et = block_reduce_1024(pet, sred);

    // ---- Phase B: sum_neg over j = 1..N-1 of exp(row0_j) + exp(extra)
    float sna = 0.f, snt = 0.f;
    for (int j = tid; j < N; j += 1024) {
        if (j == 0) continue;
        const float inv_a = 1.0f / (nv0 * fmaxf(na[j], L2EPS));
        const float inv_t = 1.0f / (nv0 * fmaxf(nt[j], L2EPS));
        sna += expf(d0a[j] * inv_a * TEMP_INV);
        snt += expf(d0t[j] * inv_t * TEMP_INV);
    }
    float sum_neg_a = block_reduce_1024(sna, sred);
    float sum_neg_t = block_reduce_1024(snt, sred);
    sum_neg_a += expf(ea / (nv1 * na0) * TEMP_INV);
    sum_neg_t += expf(et / (nv1 * nt0) * TEMP_INV);

    // ---- Phase C: loss sums
    float la = 0.f, lt = 0.f;
    for (int k = tid; k < N; k += 1024) {
        const float nvk = fmaxf(nv[k], L2EPS);
        const float pos_a = dva[k] / (nvk * fmaxf(na[k], L2EPS)) * TEMP_INV;
        const float pos_t = dvt[k] / (nvk * fmaxf(nt[k], L2EPS)) * TEMP_INV;
        float lla = logf(expf(pos_a) + sum_neg_a) - pos_a;
        float llt = logf(expf(pos_t) + sum_neg_t) - pos_t;
        if (isnan(lla)) lla = 0.f;
        if (isnan(llt)) llt = 0.f;
        la += lla;
        lt += llt;
    }
    la = block_reduce_1024(la, sred);
    lt = block_reduce_1024(lt, sred);

    if (tid == 0) {
        out[0] = la / (float)N;
        out[1] = lt / (float)N;
    }
}

extern "C" void kernel_launch(void* const* d_in, const int* in_sizes, int n_in,
                              void* d_out, int out_size, void* d_ws, size_t ws_size,
                              hipStream_t stream) {
    const float* v = (const float*)d_in[0];
    const float* a = (const float*)d_in[1];
    const float* t = (const float*)d_in[2];
    float* out = (float*)d_out;
    float* ws  = (float*)d_ws;
    const int N = in_sizes[0] / D_DIM;   // 16384

    const int blocks = (N + 3) / 4;      // one 64-lane wave per row
    nce_rowstats<<<blocks, 256, 0, stream>>>(v, a, t, ws, N);
    nce_finalize<<<1, 1024, 0, stream>>>(v, a, t, ws, out, N);
}

// Round 3
// 60.467 us; speedup vs baseline: 1.0067x; 1.0067x over previous
//
#include <hip/hip_runtime.h>
#include <math.h>

#define D_DIM 1024
#define TEMP_INV 14.285714285714286f   // 1/0.07
#define L2EPS 1e-12f

typedef float f32x4 __attribute__((ext_vector_type(4)));

// ws layout (floats):
// [0*N .. 1*N)  nv   = ||v_k||
// [1*N .. 2*N)  na   = ||a_k||
// [2*N .. 3*N)  nt   = ||t_k||
// [3*N .. 4*N)  dva  = v_k . a_k
// [4*N .. 5*N)  dvt  = v_k . t_k
// [5*N .. 6*N)  d0a  = v_0 . a_k
// [6*N .. 7*N)  d0t  = v_0 . t_k

__device__ __forceinline__ float dot4(const f32x4 p, const f32x4 q) {
    return p.x*q.x + p.y*q.y + p.z*q.z + p.w*q.w;
}

// Forced-issue 16B load at base + imm offset. Result NOT valid until the
// explicit s_waitcnt below — compiler thinks it is, hence the sched_barrier.
#define GLOAD4(dst, base, imm)                                          \
    asm volatile("global_load_dwordx4 %0, %1, off offset:" #imm         \
                 : "=v"(dst) : "v"(base))

__global__ __launch_bounds__(256) void nce_rowstats(
    const float* __restrict__ v, const float* __restrict__ a,
    const float* __restrict__ t, float* __restrict__ ws, int N)
{
    const int tid  = threadIdx.x;
    const int wave = tid >> 6;
    const int lane = tid & 63;
    const int row  = blockIdx.x * 4 + wave;
    if (row >= N) return;

    const float* vp = v + (size_t)row * D_DIM + lane * 4;
    const float* ap = a + (size_t)row * D_DIM + lane * 4;
    const float* tp = t + (size_t)row * D_DIM + lane * 4;
    const float* zp = v + lane * 4;               // row 0 of v (L1/L2 hit)

    f32x4 V0, V1, V2, V3, A0, A1, A2, A3, T0, T1, T2, T3, Z0, Z1, Z2, Z3;
    // ---- 16 loads issued back-to-back, all in flight ----
    GLOAD4(V0, vp, 0);    GLOAD4(V1, vp, 1024);
    GLOAD4(V2, vp, 2048); GLOAD4(V3, vp, 3072);
    GLOAD4(A0, ap, 0);    GLOAD4(A1, ap, 1024);
    GLOAD4(A2, ap, 2048); GLOAD4(A3, ap, 3072);
    GLOAD4(T0, tp, 0);    GLOAD4(T1, tp, 1024);
    GLOAD4(T2, tp, 2048); GLOAD4(T3, tp, 3072);
    GLOAD4(Z0, zp, 0);    GLOAD4(Z1, zp, 1024);
    GLOAD4(Z2, zp, 2048); GLOAD4(Z3, zp, 3072);

    asm volatile("s_waitcnt vmcnt(0)" ::: "memory");
    __builtin_amdgcn_sched_barrier(0);   // rule #18: keep uses below the wait

    float sv  = dot4(V0,V0) + dot4(V1,V1) + dot4(V2,V2) + dot4(V3,V3);
    float sa  = dot4(A0,A0) + dot4(A1,A1) + dot4(A2,A2) + dot4(A3,A3);
    float st  = dot4(T0,T0) + dot4(T1,T1) + dot4(T2,T2) + dot4(T3,T3);
    float dva = dot4(V0,A0) + dot4(V1,A1) + dot4(V2,A2) + dot4(V3,A3);
    float dvt = dot4(V0,T0) + dot4(V1,T1) + dot4(V2,T2) + dot4(V3,T3);
    float d0a = dot4(Z0,A0) + dot4(Z1,A1) + dot4(Z2,A2) + dot4(Z3,A3);
    float d0t = dot4(Z0,T0) + dot4(Z1,T1) + dot4(Z2,T2) + dot4(Z3,T3);

    // wave (64-lane) butterfly reduce of 7 values
    #pragma unroll
    for (int off = 32; off >= 1; off >>= 1) {
        sv  += __shfl_down(sv,  off);
        sa  += __shfl_down(sa,  off);
        st  += __shfl_down(st,  off);
        dva += __shfl_down(dva, off);
        dvt += __shfl_down(dvt, off);
        d0a += __shfl_down(d0a, off);
        d0t += __shfl_down(d0t, off);
    }

    if (lane == 0) {
        ws[0*N + row] = sqrtf(sv);
        ws[1*N + row] = sqrtf(sa);
        ws[2*N + row] = sqrtf(st);
        ws[3*N + row] = dva;
        ws[4*N + row] = dvt;
        ws[5*N + row] = d0a;
        ws[6*N + row] = d0t;
    }
}

__device__ __forceinline__ float block_reduce_1024(float val, float* sred) {
    // 1024 threads = 16 waves. sred must hold >= 16 floats.
    const int lane = threadIdx.x & 63;
    const int wave = threadIdx.x >> 6;
    __syncthreads();   // protect sred reuse across successive calls
    #pragma unroll
    for (int off = 32; off >= 1; off >>= 1) val += __shfl_down(val, off);
    if (lane == 0) sred[wave] = val;
    __syncthreads();
    float r = 0.f;
    if (wave == 0) {
        r = (lane < 16) ? sred[lane] : 0.f;
        #pragma unroll
        for (int off = 8; off >= 1; off >>= 1) r += __shfl_down(r, off);
        if (lane == 0) sred[0] = r;
    }
    __syncthreads();
    return sred[0];
}

__global__ __launch_bounds__(1024) void nce_finalize(
    const float* __restrict__ v, const float* __restrict__ a,
    const float* __restrict__ t, const float* __restrict__ ws,
    float* __restrict__ out, int N)
{
    __shared__ float sred[16];
    const int tid = threadIdx.x;

    const float* nv  = ws + 0 * (size_t)N;
    const float* na  = ws + 1 * (size_t)N;
    const float* nt  = ws + 2 * (size_t)N;
    const float* dva = ws + 3 * (size_t)N;
    const float* dvt = ws + 4 * (size_t)N;
    const float* d0a = ws + 5 * (size_t)N;
    const float* d0t = ws + 6 * (size_t)N;

    const float nv0 = fmaxf(nv[0], L2EPS);
    const float nv1 = fmaxf(nv[1], L2EPS);
    const float na0 = fmaxf(na[0], L2EPS);
    const float nt0 = fmaxf(nt[0], L2EPS);

    // ---- Phase A: extras ea = v1.a0, et = v1.t0 (D=1024, one elem/thread)
    float pea = v[D_DIM + tid] * a[tid];
    float pet = v[D_DIM + tid] * t[tid];
    const float ea = block_reduce_1024(pea, sred);
    const float et = block_reduce_1024(pet, sred);

    // ---- Phase B: sum_neg over j = 1..N-1 of exp(row0_j) + exp(extra)
    float sna = 0.f, snt = 0.f;
    for (int j = tid; j < N; j += 1024) {
        if (j == 0) continue;
        const float inv_a = 1.0f / (nv0 * fmaxf(na[j], L2EPS));
        const float inv_t = 1.0f / (nv0 * fmaxf(nt[j], L2EPS));
        sna += expf(d0a[j] * inv_a * TEMP_INV);
        snt += expf(d0t[j] * inv_t * TEMP_INV);
    }
    float sum_neg_a = block_reduce_1024(sna, sred);
    float sum_neg_t = block_reduce_1024(snt, sred);
    sum_neg_a += expf(ea / (nv1 * na0) * TEMP_INV);
    sum_neg_t += expf(et / (nv1 * nt0) * TEMP_INV);

    // ---- Phase C: loss sums
    float la = 0.f, lt = 0.f;
    for (int k = tid; k < N; k += 1024) {
        const float nvk = fmaxf(nv[k], L2EPS);
        const float pos_a = dva[k] / (nvk * fmaxf(na[k], L2EPS)) * TEMP_INV;
        const float pos_t = dvt[k] / (nvk * fmaxf(nt[k], L2EPS)) * TEMP_INV;
        float lla = logf(expf(pos_a) + sum_neg_a) - pos_a;
        float llt = logf(expf(pos_t) + sum_neg_t) - pos_t;
        if (isnan(lla)) lla = 0.f;
        if (isnan(llt)) llt = 0.f;
        la += lla;
        lt += llt;
    }
    la = block_reduce_1024(la, sred);
    lt = block_reduce_1024(lt, sred);

    if (tid == 0) {
        out[0] = la / (float)N;
        out[1] = lt / (float)N;
    }
}

extern "C" void kernel_launch(void* const* d_in, const int* in_sizes, int n_in,
                              void* d_out, int out_size, void* d_ws, size_t ws_size,
                              hipStream_t stream) {
    const float* v = (const float*)d_in[0];
    const float* a = (const float*)d_in[1];
    const float* t = (const float*)d_in[2];
    float* out = (float*)d_out;
    float* ws  = (float*)d_ws;
    const int N = in_sizes[0] / D_DIM;   // 16384

    const int blocks = (N + 3) / 4;      // one 64-lane wave per row
    nce_rowstats<<<blocks, 256, 0, stream>>>(v, a, t, ws, N);
    nce_finalize<<<1, 1024, 0, stream>>>(v, a, t, ws, out, N);
}